// Round 18
// baseline (145.838 us; speedup 1.0000x reference)
//
#include <hip/hip_runtime.h>

typedef unsigned short u16;
typedef __attribute__((ext_vector_type(4))) float f32x4;
typedef __attribute__((ext_vector_type(8))) __bf16 bf16x8;
typedef __attribute__((ext_vector_type(4))) __bf16 bf16x4;
typedef __attribute__((ext_vector_type(4))) unsigned short u16x4;
typedef __attribute__((ext_vector_type(8))) unsigned short u16x8;

// round-to-nearest-even fp32 -> bf16 (used in epilogues / converts)
static __device__ __forceinline__ u16 f2bf(float f) {
    union { float f; unsigned u; } v; v.f = f;
    unsigned r = v.u + 0x7FFFu + ((v.u >> 16) & 1u);
    return (u16)(r >> 16);
}

// v_exp_f32: D = 2^x
static __device__ __forceinline__ float exp2f_fast(float x) {
    float r; asm("v_exp_f32 %0, %1" : "=v"(r) : "v"(x)); return r;
}

// 3-input max (clang fuses to v_max3_f32)
static __device__ __forceinline__ float max3f(float a, float b, float c) {
    return fmaxf(fmaxf(a, b), c);
}

// async global->LDS, 16 bytes per lane (dest must be wave-uniform base + lane*16)
static __device__ __forceinline__ void gload16(const u16* g, u16* l) {
    __builtin_amdgcn_global_load_lds(
        (const __attribute__((address_space(1))) unsigned int*)g,
        (__attribute__((address_space(3))) unsigned int*)l, 16, 0, 0);
}

template<int N> static __device__ __forceinline__ void vm_wait() {
    if constexpr (N >= 8)      asm volatile("s_waitcnt vmcnt(8)" ::: "memory");
    else if constexpr (N == 6) asm volatile("s_waitcnt vmcnt(6)" ::: "memory");
    else if constexpr (N == 4) asm volatile("s_waitcnt vmcnt(4)" ::: "memory");
    else if constexpr (N == 3) asm volatile("s_waitcnt vmcnt(3)" ::: "memory");
    else if constexpr (N == 2) asm volatile("s_waitcnt vmcnt(2)" ::: "memory");
    else if constexpr (N == 1) asm volatile("s_waitcnt vmcnt(1)" ::: "memory");
    else                       asm volatile("s_waitcnt vmcnt(0)" ::: "memory");
}

// swizzled element offset in a [rows][64] u16 tile (flash K/V tiles)
#define SWZ64(row, ec) (((row) * 64) + ((((ec) ^ ((row) & 7))) << 3))

// ---------------- merged prep: fp32->bf16 convert + 4x weight transpose ----------------
__global__ __launch_bounds__(256) void k_prep(
    const float* __restrict__ hs, u16* __restrict__ Xb,
    const float* __restrict__ W0, const float* __restrict__ W1,
    const float* __restrict__ W2, const float* __restrict__ W3,
    u16* __restrict__ T0, u16* __restrict__ T1, u16* __restrict__ T2, u16* __restrict__ T3,
    float s0) {
    __shared__ float tile[32][33];
    const int id = blockIdx.x;
    const int tid = threadIdx.x;
    if (id < 8192) {   // ---- cvt ----
        size_t i = (size_t)id * 256 + tid;
        float4 v = ((const float4*)hs)[i];
        u16x4 o; o[0] = f2bf(v.x); o[1] = f2bf(v.y); o[2] = f2bf(v.z); o[3] = f2bf(v.w);
        *(u16x4*)(Xb + i * 4) = o;
        return;
    }
    // ---- wtrans: W [K=1024][N=1024] fp32 -> Wt [N][K] bf16 (scaled) ----
    const int wid = id - 8192;
    const int z = wid >> 10, rem = wid & 1023;
    const int n0 = (rem & 31) * 32, k0 = (rem >> 5) * 32;
    const float* W; u16* Tt; float sc;
    switch (z) {
        case 0:  W = W0; Tt = T0; sc = s0;  break;
        case 1:  W = W1; Tt = T1; sc = 1.f; break;
        case 2:  W = W2; Tt = T2; sc = 1.f; break;
        default: W = W3; Tt = T3; sc = 1.f; break;
    }
    int r = tid >> 3, c = (tid & 7) * 4;
    float4 v = *(const float4*)(W + (size_t)(k0 + r) * 1024 + n0 + c);
    tile[r][c] = v.x; tile[r][c + 1] = v.y; tile[r][c + 2] = v.z; tile[r][c + 3] = v.w;
    __syncthreads();
    u16x4 o;
    o[0] = f2bf(tile[c][r] * sc);
    o[1] = f2bf(tile[c + 1][r] * sc);
    o[2] = f2bf(tile[c + 2][r] * sc);
    o[3] = f2bf(tile[c + 3][r] * sc);
    *(u16x4*)(Tt + (size_t)(n0 + r) * 1024 + k0 + c) = o;
}

// ---------------- 256-wide GEMM (4-deep pipeline, proven best; untouched) ----------------
// BM=256, BK=32, 512 threads (8 waves). BN=256: waves 2M x 4N (wave C = 128x64);
// BN=128: 4M x 2N (wave C = 64x64). 4-deep K-tile LDS pipeline (stage 3 ahead),
// counted vmcnt(2L) once per K-tile. Involution swizzle chunk ^= (row>>1)&3 on both
// stage-source and frag-read.
// mode 0: generic; mode 1: QK split; mode 2: V^T with in-32 column permutation
// pos = g*8+hi*4+r so flash PV A-frags are contiguous b128 in register-P k-order.
template<int BN>
__global__ __launch_bounds__(512, 2) void k_g256(
    const u16* __restrict__ A, const u16* __restrict__ Bt,
    const float* __restrict__ bias, const float* __restrict__ biasK, float qscale,
    u16* __restrict__ obf, u16* __restrict__ obK, float* __restrict__ of32,
    int ldc, int bias_row, int nblk, int mode) {
    constexpr int WN = (BN == 256) ? 4 : 2;       // waves along N
    constexpr int WAVE_M = (BN == 256) ? 128 : 64;
    constexpr int M_REP = WAVE_M / 16;            // 8 or 4
    constexpr int BCALLS = BN / 128;              // 2 or 1
    constexpr int LPT = 2 + BCALLS;               // per-wave gloads per K-tile (4 or 3)
    constexpr int ASLOT = 256 * 32;               // u16 per A K-tile slot (16 KB)
    constexpr int BSLOT = BN * 32;                // u16 per B K-tile slot
    __shared__ u16 As[4 * ASLOT];
    __shared__ u16 Bs[4 * BSLOT];
    const int tid = threadIdx.x;
    const int l = tid & 63, w = tid >> 6;
    const int mw = w / WN, nw = w % WN;
    const int fr = l & 15, gg = l >> 4, f4 = gg * 4;
    // XCD-bijective swizzle (grid is always 256 = 32 per XCD)
    const int id = blockIdx.x;
    const int swz = (id & 7) * 32 + (id >> 3);
    const int bm = swz / nblk, bn = swz % nblk;
    const size_t m0 = (size_t)bm * 256, n0v = (size_t)bn * BN;

    const int srow = w * 16 + (l >> 2);
    const int schk = ((l & 3) ^ ((l >> 3) & 3)) * 8;
    const u16* agp0 = A + (m0 + srow) * 1024 + schk;
    const u16* agp1 = A + (m0 + 128 + srow) * 1024 + schk;
    const u16* bgp0 = Bt + (n0v + srow) * 1024 + schk;
    const u16* bgp1 = (BN == 256) ? Bt + (n0v + 128 + srow) * 1024 + schk : bgp0;
    const int ldst = w * 512 + l * 8;   // u16 offset within an 8KB call region

    // fragment read offsets (read-side XOR undoes the store-side XOR -> canonical k)
    const int fchk = (gg ^ ((fr >> 1) & 3)) * 8;
    int aoff[8], boff[4];
#pragma unroll
    for (int mt = 0; mt < 8; ++mt) aoff[mt] = (mw * WAVE_M + mt * 16 + fr) * 32 + fchk;
#pragma unroll
    for (int nt = 0; nt < 4; ++nt) boff[nt] = (nw * 64 + nt * 16 + fr) * 32 + fchk;

    f32x4 acc[8][4] = {};

#define PSTG(S, J)                                                              \
    gload16(agp0 + (size_t)(J) * 32, As + (S) * ASLOT + ldst);                  \
    gload16(agp1 + (size_t)(J) * 32, As + (S) * ASLOT + 4096 + ldst);           \
    gload16(bgp0 + (size_t)(J) * 32, Bs + (S) * BSLOT + ldst);                  \
    if constexpr (BN == 256)                                                    \
        gload16(bgp1 + (size_t)(J) * 32, Bs + (S) * BSLOT + 4096 + ldst);
    PSTG(0, 0) PSTG(1, 1) PSTG(2, 2)
#undef PSTG

#define TILE(S, J, VMN, STG)                                                    \
    {                                                                           \
        vm_wait<VMN>();                                                         \
        __builtin_amdgcn_s_barrier();                                           \
        bf16x8 afr[4], bfr[4];                                                  \
        _Pragma("unroll")                                                       \
        for (int nt = 0; nt < 4; ++nt)                                          \
            bfr[nt] = *(const bf16x8*)(&Bs[(S) * BSLOT + boff[nt]]);            \
        _Pragma("unroll")                                                       \
        for (int mt = 0; mt < 4; ++mt)                                          \
            afr[mt] = *(const bf16x8*)(&As[(S) * ASLOT + aoff[mt]]);            \
        if constexpr (STG) {                                                    \
            gload16(agp0 + (size_t)((J) + 3) * 32, As + (((S) + 3) & 3) * ASLOT + ldst);        \
            gload16(agp1 + (size_t)((J) + 3) * 32, As + (((S) + 3) & 3) * ASLOT + 4096 + ldst); \
            if constexpr (BN == 128)                                            \
                gload16(bgp0 + (size_t)((J) + 3) * 32, Bs + (((S) + 3) & 3) * BSLOT + ldst);    \
        }                                                                       \
        __builtin_amdgcn_s_barrier();                                           \
        asm volatile("s_waitcnt lgkmcnt(0)" ::: "memory");                      \
        __builtin_amdgcn_sched_barrier(0);                                      \
        __builtin_amdgcn_s_setprio(1);                                          \
        _Pragma("unroll")                                                       \
        for (int mt = 0; mt < 4; ++mt)                                          \
            _Pragma("unroll")                                                   \
            for (int nt = 0; nt < 4; ++nt)                                      \
                acc[mt][nt] = __builtin_amdgcn_mfma_f32_16x16x32_bf16(afr[mt], bfr[nt], acc[mt][nt], 0, 0, 0); \
        __builtin_amdgcn_s_setprio(0);                                          \
        if constexpr (BN == 256) {                                              \
            _Pragma("unroll")                                                   \
            for (int mt = 0; mt < 4; ++mt)                                      \
                afr[mt] = *(const bf16x8*)(&As[(S) * ASLOT + aoff[4 + mt]]);    \
            if constexpr (STG) {                                                \
                gload16(bgp0 + (size_t)((J) + 3) * 32, Bs + (((S) + 3) & 3) * BSLOT + ldst);        \
                gload16(bgp1 + (size_t)((J) + 3) * 32, Bs + (((S) + 3) & 3) * BSLOT + 4096 + ldst); \
            }                                                                   \
            __builtin_amdgcn_s_barrier();                                       \
            asm volatile("s_waitcnt lgkmcnt(0)" ::: "memory");                  \
            __builtin_amdgcn_sched_barrier(0);                                  \
            __builtin_amdgcn_s_setprio(1);                                      \
            _Pragma("unroll")                                                   \
            for (int mt = 0; mt < 4; ++mt)                                      \
                _Pragma("unroll")                                               \
                for (int nt = 0; nt < 4; ++nt)                                  \
                    acc[4 + mt][nt] = __builtin_amdgcn_mfma_f32_16x16x32_bf16(afr[mt], bfr[nt], acc[4 + mt][nt], 0, 0, 0); \
            __builtin_amdgcn_s_setprio(0);                                      \
        }                                                                       \
    }

#pragma unroll 1
    for (int jb = 0; jb < 28; jb += 4) {
        TILE(0, jb + 0, (2 * LPT), true)
        TILE(1, jb + 1, (2 * LPT), true)
        TILE(2, jb + 2, (2 * LPT), true)
        TILE(3, jb + 3, (2 * LPT), true)
    }
    TILE(0, 28, (2 * LPT), true)
    TILE(1, 29, (2 * LPT), false)
    TILE(2, 30, LPT, false)
    TILE(3, 31, 0, false)
#undef TILE

    // epilogue: C/D layout col = lane&15, row = (lane>>4)*4 + r  [HW-verified]
    const int mrow0 = (int)m0 + mw * WAVE_M;
    const int ncol0 = (int)n0v + nw * 64;
    if (mode == 1) {   // QK split (BN==256): cols 0..1023 -> Q (bias*qscale), 1024.. -> K
#pragma unroll
        for (int mt = 0; mt < M_REP; ++mt)
#pragma unroll
            for (int nt = 0; nt < 4; ++nt) {
                const int col = ncol0 + nt * 16 + fr;
                const int seg = col >> 10, colm = col & 1023;
                const float bb = (seg ? biasK[colm] : bias[colm] * qscale);
                u16* op = seg ? obK : obf;
#pragma unroll
                for (int r = 0; r < 4; ++r)
                    op[(size_t)(mrow0 + mt * 16 + f4 + r) * 1024 + colm] = f2bf(acc[mt][nt][r] + bb);
            }
    } else if (mode == 2) {   // V^T: row bias, in-32 column permutation for flash PV b128
#pragma unroll
        for (int mt = 0; mt < M_REP; ++mt) {
            float rb_[4];
#pragma unroll
            for (int r = 0; r < 4; ++r) rb_[r] = bias[mrow0 + mt * 16 + f4 + r];
#pragma unroll
            for (int nt = 0; nt < 4; ++nt) {
                const int col = ncol0 + nt * 16 + fr;
                const int colp = (col & ~31) | (((col >> 2) & 3) << 3) |
                                 (((col >> 4) & 1) << 2) | (col & 3);
#pragma unroll
                for (int r = 0; r < 4; ++r) {
                    const size_t row = (size_t)(mrow0 + mt * 16 + f4 + r);
                    obf[row * (size_t)ldc + colp] = f2bf(acc[mt][nt][r] + rb_[r]);
                }
            }
        }
    } else {
#pragma unroll
        for (int mt = 0; mt < M_REP; ++mt) {
            float rb_[4];
#pragma unroll
            for (int r = 0; r < 4; ++r)
                rb_[r] = bias_row ? bias[mrow0 + mt * 16 + f4 + r] : 0.f;
#pragma unroll
            for (int nt = 0; nt < 4; ++nt) {
                const int col = ncol0 + nt * 16 + fr;
                const float cb = bias_row ? 0.f : bias[col];
#pragma unroll
                for (int r = 0; r < 4; ++r) {
                    const size_t row = (size_t)(mrow0 + mt * 16 + f4 + r);
                    const float vv = acc[mt][nt][r] + cb + rb_[r];
                    if (of32) of32[row * (size_t)ldc + col] = vv;
                    else      obf[row * (size_t)ldc + col] = f2bf(vv);
                }
            }
        }
    }
}

// ---------------- flash attention: lag-1 PV, 2-tile sync windows, 4K+5V slots (72 KB) ----------------
// lsum computed on the MFMA pipe: an all-ones A-fragment row-sums P (see pv_tile).
static __device__ __forceinline__ void qk_tile(const u16* Ks, int fr, int gg,
                                               bf16x8 qA0, bf16x8 qA1, bf16x8 qB0, bf16x8 qB1,
                                               float mA, float mB, f32x4 sA[4], f32x4 sB[4]) {
    __builtin_amdgcn_s_setprio(1);
#pragma unroll
    for (int nt = 0; nt < 4; ++nt) {
        const int rk = nt * 16 + fr;
        const bf16x8 kf0 = *(const bf16x8*)(&Ks[SWZ64(rk, gg)]);
        const bf16x8 kf1 = *(const bf16x8*)(&Ks[SWZ64(rk, gg + 4)]);
        f32x4 z = {-mA, -mA, -mA, -mA};
        z = __builtin_amdgcn_mfma_f32_16x16x32_bf16(kf0, qA0, z, 0, 0, 0);
        z = __builtin_amdgcn_mfma_f32_16x16x32_bf16(kf1, qA1, z, 0, 0, 0);
        sA[nt] = z;
        f32x4 y = {-mB, -mB, -mB, -mB};
        y = __builtin_amdgcn_mfma_f32_16x16x32_bf16(kf0, qB0, y, 0, 0, 0);
        y = __builtin_amdgcn_mfma_f32_16x16x32_bf16(kf1, qB1, y, 0, 0, 0);
        sB[nt] = y;
    }
    __builtin_amdgcn_s_setprio(0);
}

// softmax: no cross-lane ops and NO sum in the common path (sum moves to the MFMA pipe);
// max via v_max3 tree. Rare rescale also scales the MFMA sum accumulator (exact: at this
// point `sum` contains tiles 0..t-1, same coverage as a scalar lsum would have).
static __device__ __forceinline__ void sm_tile(const f32x4 s[4], f32x4 o[4], f32x4& sum,
                                               float& m, bf16x4 p[4]) {
    const float x0 = max3f(s[0][0], s[0][1], s[0][2]);
    const float x1 = max3f(s[0][3], s[1][0], s[1][1]);
    const float x2 = max3f(s[1][2], s[1][3], s[2][0]);
    const float x3 = max3f(s[2][1], s[2][2], s[2][3]);
    const float x4 = max3f(s[3][0], s[3][1], s[3][2]);
    const float mymax = fmaxf(max3f(x0, x1, x2), max3f(x3, x4, s[3][3]));
#pragma unroll
    for (int nt = 0; nt < 4; ++nt)
#pragma unroll
        for (int r = 0; r < 4; ++r) p[nt][r] = (__bf16)exp2f_fast(s[nt][r]);
    if (__builtin_expect(__any(mymax > 11.0f), 0)) {   // wave-uniform rare path
        float rm = fmaxf(mymax, __shfl_xor(mymax, 16, 64));
        rm = fmaxf(rm, __shfl_xor(rm, 32, 64));
        const float d = fmaxf(rm, 0.f);
        const float fac = exp2f_fast(-d);
        m += d;
#pragma unroll
        for (int mt = 0; mt < 4; ++mt)
#pragma unroll
            for (int r = 0; r < 4; ++r) o[mt][r] *= fac;
#pragma unroll
        for (int r = 0; r < 4; ++r) sum[r] *= fac;
#pragma unroll
        for (int nt = 0; nt < 4; ++nt)
#pragma unroll
            for (int r = 0; r < 4; ++r) p[nt][r] = (__bf16)exp2f_fast(s[nt][r] - d);
    }
}

// PV with b128 V-frag reads (Vt2 stored k-permuted so register-P k-order is contiguous).
// The extra ones-A MFMA accumulates the P row sums (denominator) on the matrix pipe;
// the all-ones fragment is invariant under the k-permutation.
static __device__ __forceinline__ void pv_tile(const u16* Vs, int fr, int gg,
                                               const bf16x4 pA[4], const bf16x4 pB[4],
                                               f32x4 oA[4], f32x4 oB[4],
                                               f32x4& sumA, f32x4& sumB, bf16x8 ones) {
    const bf16x8 BA0 = __builtin_shufflevector(pA[0], pA[1], 0, 1, 2, 3, 4, 5, 6, 7);
    const bf16x8 BA1 = __builtin_shufflevector(pA[2], pA[3], 0, 1, 2, 3, 4, 5, 6, 7);
    const bf16x8 BB0 = __builtin_shufflevector(pB[0], pB[1], 0, 1, 2, 3, 4, 5, 6, 7);
    const bf16x8 BB1 = __builtin_shufflevector(pB[2], pB[3], 0, 1, 2, 3, 4, 5, 6, 7);
    __builtin_amdgcn_s_setprio(1);
#pragma unroll
    for (int mt = 0; mt < 4; ++mt) {
        const int rv = mt * 16 + fr;
        const bf16x8 vk0 = *(const bf16x8*)(&Vs[SWZ64(rv, gg)]);
        const bf16x8 vk1 = *(const bf16x8*)(&Vs[SWZ64(rv, gg + 4)]);
        oA[mt] = __builtin_amdgcn_mfma_f32_16x16x32_bf16(vk0, BA0, oA[mt], 0, 0, 0);
        oA[mt] = __builtin_amdgcn_mfma_f32_16x16x32_bf16(vk1, BA1, oA[mt], 0, 0, 0);
        oB[mt] = __builtin_amdgcn_mfma_f32_16x16x32_bf16(vk0, BB0, oB[mt], 0, 0, 0);
        oB[mt] = __builtin_amdgcn_mfma_f32_16x16x32_bf16(vk1, BB1, oB[mt], 0, 0, 0);
    }
    sumA = __builtin_amdgcn_mfma_f32_16x16x32_bf16(ones, BA0, sumA, 0, 0, 0);
    sumA = __builtin_amdgcn_mfma_f32_16x16x32_bf16(ones, BA1, sumA, 0, 0, 0);
    sumB = __builtin_amdgcn_mfma_f32_16x16x32_bf16(ones, BB0, sumB, 0, 0, 0);
    sumB = __builtin_amdgcn_mfma_f32_16x16x32_bf16(ones, BB1, sumB, 0, 0, 0);
    __builtin_amdgcn_s_setprio(0);
}

// 1D grid 1024 blocks (XCD-bijective swizzle). 4 waves, 32 q-rows/wave (groups A/B).
// 4-slot K + 5-slot V rotation = 72 KB (2 blocks/CU). SYNC WINDOWS OF 2 SUB-TILES:
// one vmcnt(2)+s_barrier per window (half the barriers of the 1-tile version).
// Staging at sub-tile t: K(t+2)->slot (t+2)&3, V(t+2)->slot (t+2)%5.
// Even-entry ledger: 8 outstanding {K(t),V(t),K(t+1),V(t+1)}; vmcnt(2) lands
// K(t),V(t),K(t+1) for EVERY wave before the barrier -> all mid-window cross-wave
// reads (QK(t), QK(t+1), pv V(t-1), pv V(t)) are published; V(t+1) stays in flight
// and is covered by the next entry. First entry vmcnt(1) (prologue = 4 calls).
// Slot liveness: K/V writes vs prior reads are always in different windows.
__global__ __launch_bounds__(256, 2) void k_flash(const u16* __restrict__ Q, const u16* __restrict__ K,
                                                  const u16* __restrict__ Vt2, u16* __restrict__ O) {
    __shared__ u16 Ks[4][64 * 64];
    __shared__ u16 Vs[5][64 * 64];
    const int tid = threadIdx.x;
    const int l = tid & 63, w = tid >> 6;
    const int id = blockIdx.x;
    const int swz = (id & 7) * 128 + (id >> 3);      // bijective XCD swizzle (1024 % 8 == 0)
    const int bh = swz >> 3, qt = swz & 7;
    const int b = bh >> 4, h = bh & 15;
    const int qw = qt * 128 + w * 32;
    const int fr = l & 15, gg = l >> 4, f4 = gg * 4, f8 = gg * 8;

    const u16* qpA = Q + ((size_t)(b * 1024 + qw + fr)) * 1024 + h * 64 + f8;
    const u16* qpB = qpA + 16 * 1024;
    const bf16x8 qA0 = *(const bf16x8*)qpA;
    const bf16x8 qA1 = *(const bf16x8*)(qpA + 32);
    const bf16x8 qB0 = *(const bf16x8*)qpB;
    const bf16x8 qB1 = *(const bf16x8*)(qpB + 32);

    const __bf16 one1 = (__bf16)1.0f;
    const bf16x8 ones = {one1, one1, one1, one1, one1, one1, one1, one1};

    const int jj0 = w * 2, jj1 = w * 2 + 1;
    const int sr0 = jj0 * 8 + (l >> 3), sr1 = jj1 * 8 + (l >> 3);
    const int sc = ((l & 7) ^ (l >> 3)) * 8;
    const u16* kg0 = K + ((size_t)(b * 1024 + sr0)) * 1024 + h * 64 + sc;
    const u16* kg1 = K + ((size_t)(b * 1024 + sr1)) * 1024 + h * 64 + sc;
    const u16* vg0 = Vt2 + ((size_t)(h * 64 + sr0)) * 8192 + b * 1024 + sc;
    const u16* vg1 = Vt2 + ((size_t)(h * 64 + sr1)) * 8192 + b * 1024 + sc;
    const int lk0 = jj0 * 512 + l * 8, lk1 = jj1 * 512 + l * 8;

#define FSTGK(S, kt)                                        \
    gload16(kg0 + (size_t)(kt) * 1024, Ks[S] + lk0);        \
    gload16(kg1 + (size_t)(kt) * 1024, Ks[S] + lk1);
#define FSTGV(S, kt)                                        \
    gload16(vg0 + (kt), Vs[S] + lk0);                       \
    gload16(vg1 + (kt), Vs[S] + lk1);

    f32x4 oA[4] = {}, oB[4] = {};
    f32x4 sumA = {0.f, 0.f, 0.f, 0.f}, sumB = {0.f, 0.f, 0.f, 0.f};
    float mA = 0.f, mB = 0.f;                       // running log2-domain max offsets
    bf16x4 p0A[4], p0B[4], p1A[4], p1B[4];          // ping-pong P sets (static names)

    // prologue: K(0), V(0), K(1), V(1)  [issue order is the vmcnt ledger]
    FSTGK(0, 0) FSTGV(0, 0) FSTGK(1, 64) FSTGV(1, 64)

// SYNC: 0 = none, 1 = vmcnt(1)+barrier (first window), 2 = vmcnt(2)+barrier
#define FITER(T, QS, PS, KS, VS, PCA, PCB, PPA, PPB, DOPV, DOSTG, SYNC)      \
    {                                                                        \
        if (SYNC == 1) { vm_wait<1>(); __builtin_amdgcn_s_barrier(); }       \
        if (SYNC == 2) { vm_wait<2>(); __builtin_amdgcn_s_barrier(); }       \
        f32x4 sA[4], sB[4];                                                  \
        qk_tile(Ks[QS], fr, gg, qA0, qA1, qB0, qB1, mA, mB, sA, sB);         \
        if (DOSTG) { FSTGK(KS, ((T) + 2) * 64) FSTGV(VS, ((T) + 2) * 64) }   \
        if (DOPV) pv_tile(Vs[PS], fr, gg, PPA, PPB, oA, oB, sumA, sumB, ones); \
        sm_tile(sA, oA, sumA, mA, PCA);                                      \
        sm_tile(sB, oB, sumB, mB, PCB);                                      \
    }

    //     T  QS  PS  KS  VS   Pcur      Pprev     PV STG SYNC
    FITER( 0,  0,  0,  2,  2, p0A, p0B, p1A, p1B,  0,  1,  1)
    FITER( 1,  1,  0,  3,  3, p1A, p1B, p0A, p0B,  1,  1,  0)
    FITER( 2,  2,  1,  0,  4, p0A, p0B, p1A, p1B,  1,  1,  2)
    FITER( 3,  3,  2,  1,  0, p1A, p1B, p0A, p0B,  1,  1,  0)
    FITER( 4,  0,  3,  2,  1, p0A, p0B, p1A, p1B,  1,  1,  2)
    FITER( 5,  1,  4,  3,  2, p1A, p1B, p0A, p0B,  1,  1,  0)
    FITER( 6,  2,  0,  0,  3, p0A, p0B, p1A, p1B,  1,  1,  2)
    FITER( 7,  3,  1,  1,  4, p1A, p1B, p0A, p0B,  1,  1,  0)
    FITER( 8,  0,  2,  2,  0, p0A, p0B, p1A, p1B,  1,  1,  2)
    FITER( 9,  1,  3,  3,  1, p1A, p1B, p0A, p0B,  1,  1,  0)
    FITER(10,  2,  4,  0,  2, p0A, p0B, p1A, p1B,  1,  1,  2)
    FITER(11,  3,  0,  1,  3, p1A, p1B, p0A, p0B,  1,  1,  0)
    FITER(12,  0,  1,  2,  4, p0A, p0B, p1A, p1B,  1,  1,  2)
    FITER(13,  1,  2,  3,  0, p1A, p1B, p0A, p0B,  1,  1,  0)
    FITER(14,  2,  3,  0,  0, p0A, p0B, p1A, p1B,  1,  0,  2)
    FITER(15,  3,  4,  0,  0, p1A, p1B, p0A, p0B,  1,  0,  0)
#undef FITER
    // drain: PV of tile 15; V(15) sits in Vs[15 % 5 = 0] (staged at T=13)
    vm_wait<0>();
    __builtin_amdgcn_s_barrier();
    pv_tile(Vs[0], fr, gg, p1A, p1B, oA, oB, sumA, sumB, ones);
#undef FSTGK
#undef FSTGV

    // epilogue: MFMA already summed the denominator across all 64 k per tile
    // (every C/D row equals the row sum; element 0 of this lane's acc suffices).
    const float ivA = 1.0f / sumA[0], ivB = 1.0f / sumB[0];
    u16* opA = O + ((size_t)(b * 1024 + qw + fr)) * 1024 + h * 64;
    u16* opB = opA + 16 * 1024;
#pragma unroll
    for (int mt = 0; mt < 4; ++mt) {
        u16x4 oa, ob;
#pragma unroll
        for (int r = 0; r < 4; ++r) { oa[r] = f2bf(oA[mt][r] * ivA); ob[r] = f2bf(oB[mt][r] * ivB); }
        *(u16x4*)(opA + mt * 16 + f4) = oa;
        *(u16x4*)(opB + mt * 16 + f4) = ob;
    }
}

extern "C" void kernel_launch(void* const* d_in, const int* in_sizes, int n_in,
                              void* d_out, int out_size, void* d_ws, size_t ws_size,
                              hipStream_t stream) {
    (void)in_sizes; (void)n_in; (void)out_size; (void)ws_size;
    const float* hs = (const float*)d_in[0];
    const float* Wq = (const float*)d_in[1];
    const float* bq = (const float*)d_in[2];
    const float* Wk = (const float*)d_in[3];
    const float* bk = (const float*)d_in[4];
    const float* Wv = (const float*)d_in[5];
    const float* bv = (const float*)d_in[6];
    const float* Wo = (const float*)d_in[7];
    const float* bo = (const float*)d_in[8];
    float* out = (float*)d_out;
    char* ws = (char*)d_ws;
    const size_t MB = 1024ull * 1024ull;
    u16* Xb  = (u16*)(ws);            // 16 MB (dead after V^T GEMM; reused as attn output Ob)
    u16* Wqt = (u16*)(ws + 16 * MB);  // 2 MB each; Wqt+Wkt adjacent => stacked [2048][1024]
    u16* Wkt = (u16*)(ws + 18 * MB);
    u16* Wvt = (u16*)(ws + 20 * MB);
    u16* Wot = (u16*)(ws + 22 * MB);
    u16* Qb  = (u16*)(ws + 24 * MB);  // 16 MB
    u16* Kb  = (u16*)(ws + 40 * MB);  // 16 MB
    u16* Vt2 = (u16*)(ws + 56 * MB);  // 16 MB: V^T[n][t-permuted], ld=8192 -> 72 MB total
    u16* Ob  = Xb;

    // HD^-0.5 * log2(e) folded into Wq and bq (softmax runs in log2 domain)
    const float SCALE_Q = 0.125f * 1.4426950408889634f;

    // merged convert + 4x weight transpose (independent memory-bound work, one launch)
    k_prep<<<dim3(12288), dim3(256), 0, stream>>>(hs, Xb, Wq, Wk, Wv, Wo,
                                                  Wqt, Wkt, Wvt, Wot, SCALE_Q);
    // fused Q+K projection: M=8192, N=2048 over stacked [Wqt;Wkt]; 32x8 = 256 blocks
    k_g256<256><<<dim3(256), dim3(512), 0, stream>>>(Xb, Wqt, bq, bk, SCALE_Q,
                                                     Qb, Kb, nullptr, 1024, 0, 8, 1);
    // V^T = Wv^T * X^T (k-permuted cols): A = Wvt (M=1024), Bt = Xb (N=8192); 4x64 blocks
    k_g256<128><<<dim3(256), dim3(512), 0, stream>>>(Wvt, Xb, bv, nullptr, 1.f,
                                                     Vt2, nullptr, nullptr, 8192, 1, 64, 2);
    k_flash<<<dim3(1024), dim3(256), 0, stream>>>(Qb, Kb, Vt2, Ob);
    // output projection: M=8192, N=1024, f32 out; 32x8 = 256 blocks
    k_g256<128><<<dim3(256), dim3(512), 0, stream>>>(Ob, Wot, bo, nullptr, 1.f,
                                                     nullptr, nullptr, out, 1024, 0, 8, 0);
}

// Round 19
// 144.751 us; speedup vs baseline: 1.0075x; 1.0075x over previous
//
#include <hip/hip_runtime.h>

typedef unsigned short u16;
typedef __attribute__((ext_vector_type(4))) float f32x4;
typedef __attribute__((ext_vector_type(8))) __bf16 bf16x8;
typedef __attribute__((ext_vector_type(4))) __bf16 bf16x4;
typedef __attribute__((ext_vector_type(4))) unsigned short u16x4;
typedef __attribute__((ext_vector_type(8))) unsigned short u16x8;

// round-to-nearest-even fp32 -> bf16 (used in epilogues / converts)
static __device__ __forceinline__ u16 f2bf(float f) {
    union { float f; unsigned u; } v; v.f = f;
    unsigned r = v.u + 0x7FFFu + ((v.u >> 16) & 1u);
    return (u16)(r >> 16);
}

// v_exp_f32: D = 2^x
static __device__ __forceinline__ float exp2f_fast(float x) {
    float r; asm("v_exp_f32 %0, %1" : "=v"(r) : "v"(x)); return r;
}

// 3-input max (clang fuses to v_max3_f32)
static __device__ __forceinline__ float max3f(float a, float b, float c) {
    return fmaxf(fmaxf(a, b), c);
}

// async global->LDS, 16 bytes per lane (dest must be wave-uniform base + lane*16)
static __device__ __forceinline__ void gload16(const u16* g, u16* l) {
    __builtin_amdgcn_global_load_lds(
        (const __attribute__((address_space(1))) unsigned int*)g,
        (__attribute__((address_space(3))) unsigned int*)l, 16, 0, 0);
}

template<int N> static __device__ __forceinline__ void vm_wait() {
    if constexpr (N >= 8)      asm volatile("s_waitcnt vmcnt(8)" ::: "memory");
    else if constexpr (N == 6) asm volatile("s_waitcnt vmcnt(6)" ::: "memory");
    else if constexpr (N == 4) asm volatile("s_waitcnt vmcnt(4)" ::: "memory");
    else if constexpr (N == 3) asm volatile("s_waitcnt vmcnt(3)" ::: "memory");
    else if constexpr (N == 2) asm volatile("s_waitcnt vmcnt(2)" ::: "memory");
    else                       asm volatile("s_waitcnt vmcnt(0)" ::: "memory");
}

// swizzled element offset in a [rows][64] u16 tile (flash K/V tiles)
#define SWZ64(row, ec) (((row) * 64) + ((((ec) ^ ((row) & 7))) << 3))

// ---------------- merged prep: fp32->bf16 convert + 4x weight transpose ----------------
__global__ __launch_bounds__(256) void k_prep(
    const float* __restrict__ hs, u16* __restrict__ Xb,
    const float* __restrict__ W0, const float* __restrict__ W1,
    const float* __restrict__ W2, const float* __restrict__ W3,
    u16* __restrict__ T0, u16* __restrict__ T1, u16* __restrict__ T2, u16* __restrict__ T3,
    float s0) {
    __shared__ float tile[32][33];
    const int id = blockIdx.x;
    const int tid = threadIdx.x;
    if (id < 8192) {   // ---- cvt ----
        size_t i = (size_t)id * 256 + tid;
        float4 v = ((const float4*)hs)[i];
        u16x4 o; o[0] = f2bf(v.x); o[1] = f2bf(v.y); o[2] = f2bf(v.z); o[3] = f2bf(v.w);
        *(u16x4*)(Xb + i * 4) = o;
        return;
    }
    // ---- wtrans: W [K=1024][N=1024] fp32 -> Wt [N][K] bf16 (scaled) ----
    const int wid = id - 8192;
    const int z = wid >> 10, rem = wid & 1023;
    const int n0 = (rem & 31) * 32, k0 = (rem >> 5) * 32;
    const float* W; u16* Tt; float sc;
    switch (z) {
        case 0:  W = W0; Tt = T0; sc = s0;  break;
        case 1:  W = W1; Tt = T1; sc = 1.f; break;
        case 2:  W = W2; Tt = T2; sc = 1.f; break;
        default: W = W3; Tt = T3; sc = 1.f; break;
    }
    int r = tid >> 3, c = (tid & 7) * 4;
    float4 v = *(const float4*)(W + (size_t)(k0 + r) * 1024 + n0 + c);
    tile[r][c] = v.x; tile[r][c + 1] = v.y; tile[r][c + 2] = v.z; tile[r][c + 3] = v.w;
    __syncthreads();
    u16x4 o;
    o[0] = f2bf(tile[c][r] * sc);
    o[1] = f2bf(tile[c + 1][r] * sc);
    o[2] = f2bf(tile[c + 2][r] * sc);
    o[3] = f2bf(tile[c + 3][r] * sc);
    *(u16x4*)(Tt + (size_t)(n0 + r) * 1024 + k0 + c) = o;
}

// ---------------- 256-wide GEMM (4-deep pipeline, proven best) ----------------
// BM=256, BK=32, 512 threads (8 waves). BN=256: waves 2M x 4N (wave C = 128x64);
// BN=128: 4M x 2N (wave C = 64x64). 4-deep K-tile LDS pipeline (stage 3 ahead),
// counted vmcnt(2L) once per K-tile. Involution swizzle chunk ^= (row>>1)&3 on both
// stage-source and frag-read.
// mode 0: generic; mode 1: QK split; mode 2: V^T with in-32 column permutation
// pos = g*8+hi*4+r so flash PV A-frags are contiguous b128 in register-P k-order.
template<int BN>
__global__ __launch_bounds__(512, 2) void k_g256(
    const u16* __restrict__ A, const u16* __restrict__ Bt,
    const float* __restrict__ bias, const float* __restrict__ biasK, float qscale,
    u16* __restrict__ obf, u16* __restrict__ obK, float* __restrict__ of32,
    int ldc, int bias_row, int nblk, int mode) {
    constexpr int WN = (BN == 256) ? 4 : 2;       // waves along N
    constexpr int WAVE_M = (BN == 256) ? 128 : 64;
    constexpr int M_REP = WAVE_M / 16;            // 8 or 4
    constexpr int BCALLS = BN / 128;              // 2 or 1
    constexpr int LPT = 2 + BCALLS;               // per-wave gloads per K-tile (4 or 3)
    constexpr int ASLOT = 256 * 32;               // u16 per A K-tile slot (16 KB)
    constexpr int BSLOT = BN * 32;                // u16 per B K-tile slot
    __shared__ u16 As[4 * ASLOT];
    __shared__ u16 Bs[4 * BSLOT];
    const int tid = threadIdx.x;
    const int l = tid & 63, w = tid >> 6;
    const int mw = w / WN, nw = w % WN;
    const int fr = l & 15, gg = l >> 4, f4 = gg * 4;
    // XCD-bijective swizzle (grid is always 256 = 32 per XCD)
    const int id = blockIdx.x;
    const int swz = (id & 7) * 32 + (id >> 3);
    const int bm = swz / nblk, bn = swz % nblk;
    const size_t m0 = (size_t)bm * 256, n0v = (size_t)bn * BN;

    const int srow = w * 16 + (l >> 2);
    const int schk = ((l & 3) ^ ((l >> 3) & 3)) * 8;
    const u16* agp0 = A + (m0 + srow) * 1024 + schk;
    const u16* agp1 = A + (m0 + 128 + srow) * 1024 + schk;
    const u16* bgp0 = Bt + (n0v + srow) * 1024 + schk;
    const u16* bgp1 = (BN == 256) ? Bt + (n0v + 128 + srow) * 1024 + schk : bgp0;
    const int ldst = w * 512 + l * 8;   // u16 offset within an 8KB call region

    // fragment read offsets (read-side XOR undoes the store-side XOR -> canonical k)
    const int fchk = (gg ^ ((fr >> 1) & 3)) * 8;
    int aoff[8], boff[4];
#pragma unroll
    for (int mt = 0; mt < 8; ++mt) aoff[mt] = (mw * WAVE_M + mt * 16 + fr) * 32 + fchk;
#pragma unroll
    for (int nt = 0; nt < 4; ++nt) boff[nt] = (nw * 64 + nt * 16 + fr) * 32 + fchk;

    f32x4 acc[8][4] = {};

#define PSTG(S, J)                                                              \
    gload16(agp0 + (size_t)(J) * 32, As + (S) * ASLOT + ldst);                  \
    gload16(agp1 + (size_t)(J) * 32, As + (S) * ASLOT + 4096 + ldst);           \
    gload16(bgp0 + (size_t)(J) * 32, Bs + (S) * BSLOT + ldst);                  \
    if constexpr (BN == 256)                                                    \
        gload16(bgp1 + (size_t)(J) * 32, Bs + (S) * BSLOT + 4096 + ldst);
    PSTG(0, 0) PSTG(1, 1) PSTG(2, 2)
#undef PSTG

#define TILE(S, J, VMN, STG)                                                    \
    {                                                                           \
        vm_wait<VMN>();                                                         \
        __builtin_amdgcn_s_barrier();                                           \
        bf16x8 afr[4], bfr[4];                                                  \
        _Pragma("unroll")                                                       \
        for (int nt = 0; nt < 4; ++nt)                                          \
            bfr[nt] = *(const bf16x8*)(&Bs[(S) * BSLOT + boff[nt]]);            \
        _Pragma("unroll")                                                       \
        for (int mt = 0; mt < 4; ++mt)                                          \
            afr[mt] = *(const bf16x8*)(&As[(S) * ASLOT + aoff[mt]]);            \
        if constexpr (STG) {                                                    \
            gload16(agp0 + (size_t)((J) + 3) * 32, As + (((S) + 3) & 3) * ASLOT + ldst);        \
            gload16(agp1 + (size_t)((J) + 3) * 32, As + (((S) + 3) & 3) * ASLOT + 4096 + ldst); \
            if constexpr (BN == 128)                                            \
                gload16(bgp0 + (size_t)((J) + 3) * 32, Bs + (((S) + 3) & 3) * BSLOT + ldst);    \
        }                                                                       \
        __builtin_amdgcn_s_barrier();                                           \
        asm volatile("s_waitcnt lgkmcnt(0)" ::: "memory");                      \
        __builtin_amdgcn_sched_barrier(0);                                      \
        __builtin_amdgcn_s_setprio(1);                                          \
        _Pragma("unroll")                                                       \
        for (int mt = 0; mt < 4; ++mt)                                          \
            _Pragma("unroll")                                                   \
            for (int nt = 0; nt < 4; ++nt)                                      \
                acc[mt][nt] = __builtin_amdgcn_mfma_f32_16x16x32_bf16(afr[mt], bfr[nt], acc[mt][nt], 0, 0, 0); \
        __builtin_amdgcn_s_setprio(0);                                          \
        if constexpr (BN == 256) {                                              \
            _Pragma("unroll")                                                   \
            for (int mt = 0; mt < 4; ++mt)                                      \
                afr[mt] = *(const bf16x8*)(&As[(S) * ASLOT + aoff[4 + mt]]);    \
            if constexpr (STG) {                                                \
                gload16(bgp0 + (size_t)((J) + 3) * 32, Bs + (((S) + 3) & 3) * BSLOT + ldst);        \
                gload16(bgp1 + (size_t)((J) + 3) * 32, Bs + (((S) + 3) & 3) * BSLOT + 4096 + ldst); \
            }                                                                   \
            __builtin_amdgcn_s_barrier();                                       \
            asm volatile("s_waitcnt lgkmcnt(0)" ::: "memory");                  \
            __builtin_amdgcn_sched_barrier(0);                                  \
            __builtin_amdgcn_s_setprio(1);                                      \
            _Pragma("unroll")                                                   \
            for (int mt = 0; mt < 4; ++mt)                                      \
                _Pragma("unroll")                                               \
                for (int nt = 0; nt < 4; ++nt)                                  \
                    acc[4 + mt][nt] = __builtin_amdgcn_mfma_f32_16x16x32_bf16(afr[mt], bfr[nt], acc[4 + mt][nt], 0, 0, 0); \
            __builtin_amdgcn_s_setprio(0);                                      \
        }                                                                       \
    }

#pragma unroll 1
    for (int jb = 0; jb < 28; jb += 4) {
        TILE(0, jb + 0, (2 * LPT), true)
        TILE(1, jb + 1, (2 * LPT), true)
        TILE(2, jb + 2, (2 * LPT), true)
        TILE(3, jb + 3, (2 * LPT), true)
    }
    TILE(0, 28, (2 * LPT), true)
    TILE(1, 29, (2 * LPT), false)
    TILE(2, 30, LPT, false)
    TILE(3, 31, 0, false)
#undef TILE

    // epilogue: C/D layout col = lane&15, row = (lane>>4)*4 + r  [HW-verified]
    const int mrow0 = (int)m0 + mw * WAVE_M;
    const int ncol0 = (int)n0v + nw * 64;
    if (mode == 1) {   // QK split (BN==256): cols 0..1023 -> Q (bias*qscale), 1024.. -> K
#pragma unroll
        for (int mt = 0; mt < M_REP; ++mt)
#pragma unroll
            for (int nt = 0; nt < 4; ++nt) {
                const int col = ncol0 + nt * 16 + fr;
                const int seg = col >> 10, colm = col & 1023;
                const float bb = (seg ? biasK[colm] : bias[colm] * qscale);
                u16* op = seg ? obK : obf;
#pragma unroll
                for (int r = 0; r < 4; ++r)
                    op[(size_t)(mrow0 + mt * 16 + f4 + r) * 1024 + colm] = f2bf(acc[mt][nt][r] + bb);
            }
    } else if (mode == 2) {   // V^T: row bias, in-32 column permutation for flash PV b128
#pragma unroll
        for (int mt = 0; mt < M_REP; ++mt) {
            float rb_[4];
#pragma unroll
            for (int r = 0; r < 4; ++r) rb_[r] = bias[mrow0 + mt * 16 + f4 + r];
#pragma unroll
            for (int nt = 0; nt < 4; ++nt) {
                const int col = ncol0 + nt * 16 + fr;
                const int colp = (col & ~31) | (((col >> 2) & 3) << 3) |
                                 (((col >> 4) & 1) << 2) | (col & 3);
#pragma unroll
                for (int r = 0; r < 4; ++r) {
                    const size_t row = (size_t)(mrow0 + mt * 16 + f4 + r);
                    obf[row * (size_t)ldc + colp] = f2bf(acc[mt][nt][r] + rb_[r]);
                }
            }
        }
    } else {
#pragma unroll
        for (int mt = 0; mt < M_REP; ++mt) {
            float rb_[4];
#pragma unroll
            for (int r = 0; r < 4; ++r)
                rb_[r] = bias_row ? bias[mrow0 + mt * 16 + f4 + r] : 0.f;
#pragma unroll
            for (int nt = 0; nt < 4; ++nt) {
                const int col = ncol0 + nt * 16 + fr;
                const float cb = bias_row ? 0.f : bias[col];
#pragma unroll
                for (int r = 0; r < 4; ++r) {
                    const size_t row = (size_t)(mrow0 + mt * 16 + f4 + r);
                    const float vv = acc[mt][nt][r] + cb + rb_[r];
                    if (of32) of32[row * (size_t)ldc + col] = vv;
                    else      obf[row * (size_t)ldc + col] = f2bf(vv);
                }
            }
        }
    }
}

// ---------------- flash attention: T15 lag-1 PV pipeline, 2K+3V slots (40 KB) ----------------
// lsum computed on the MFMA pipe: an all-ones A-fragment row-sums P (see pv_tile).
static __device__ __forceinline__ void qk_tile(const u16* Ks, int fr, int gg,
                                               bf16x8 qA0, bf16x8 qA1, bf16x8 qB0, bf16x8 qB1,
                                               float mA, float mB, f32x4 sA[4], f32x4 sB[4]) {
    __builtin_amdgcn_s_setprio(1);
#pragma unroll
    for (int nt = 0; nt < 4; ++nt) {
        const int rk = nt * 16 + fr;
        const bf16x8 kf0 = *(const bf16x8*)(&Ks[SWZ64(rk, gg)]);
        const bf16x8 kf1 = *(const bf16x8*)(&Ks[SWZ64(rk, gg + 4)]);
        f32x4 z = {-mA, -mA, -mA, -mA};
        z = __builtin_amdgcn_mfma_f32_16x16x32_bf16(kf0, qA0, z, 0, 0, 0);
        z = __builtin_amdgcn_mfma_f32_16x16x32_bf16(kf1, qA1, z, 0, 0, 0);
        sA[nt] = z;
        f32x4 y = {-mB, -mB, -mB, -mB};
        y = __builtin_amdgcn_mfma_f32_16x16x32_bf16(kf0, qB0, y, 0, 0, 0);
        y = __builtin_amdgcn_mfma_f32_16x16x32_bf16(kf1, qB1, y, 0, 0, 0);
        sB[nt] = y;
    }
    __builtin_amdgcn_s_setprio(0);
}

// softmax: no cross-lane ops and NO sum in the common path (sum moves to the MFMA pipe);
// max via v_max3 tree. Rare rescale also scales the MFMA sum accumulator (exact: at this
// point `sum` contains tiles 0..t-1, same coverage as a scalar lsum would have).
static __device__ __forceinline__ void sm_tile(const f32x4 s[4], f32x4 o[4], f32x4& sum,
                                               float& m, bf16x4 p[4]) {
    const float x0 = max3f(s[0][0], s[0][1], s[0][2]);
    const float x1 = max3f(s[0][3], s[1][0], s[1][1]);
    const float x2 = max3f(s[1][2], s[1][3], s[2][0]);
    const float x3 = max3f(s[2][1], s[2][2], s[2][3]);
    const float x4 = max3f(s[3][0], s[3][1], s[3][2]);
    const float mymax = fmaxf(max3f(x0, x1, x2), max3f(x3, x4, s[3][3]));
#pragma unroll
    for (int nt = 0; nt < 4; ++nt)
#pragma unroll
        for (int r = 0; r < 4; ++r) p[nt][r] = (__bf16)exp2f_fast(s[nt][r]);
    if (__builtin_expect(__any(mymax > 11.0f), 0)) {   // wave-uniform rare path
        float rm = fmaxf(mymax, __shfl_xor(mymax, 16, 64));
        rm = fmaxf(rm, __shfl_xor(rm, 32, 64));
        const float d = fmaxf(rm, 0.f);
        const float fac = exp2f_fast(-d);
        m += d;
#pragma unroll
        for (int mt = 0; mt < 4; ++mt)
#pragma unroll
            for (int r = 0; r < 4; ++r) o[mt][r] *= fac;
#pragma unroll
        for (int r = 0; r < 4; ++r) sum[r] *= fac;
#pragma unroll
        for (int nt = 0; nt < 4; ++nt)
#pragma unroll
            for (int r = 0; r < 4; ++r) p[nt][r] = (__bf16)exp2f_fast(s[nt][r] - d);
    }
}

// PV with b128 V-frag reads (Vt2 stored k-permuted so register-P k-order is contiguous).
// The extra ones-A MFMA accumulates the P row sums (denominator) on the matrix pipe;
// the all-ones fragment is invariant under the k-permutation.
static __device__ __forceinline__ void pv_tile(const u16* Vs, int fr, int gg,
                                               const bf16x4 pA[4], const bf16x4 pB[4],
                                               f32x4 oA[4], f32x4 oB[4],
                                               f32x4& sumA, f32x4& sumB, bf16x8 ones) {
    const bf16x8 BA0 = __builtin_shufflevector(pA[0], pA[1], 0, 1, 2, 3, 4, 5, 6, 7);
    const bf16x8 BA1 = __builtin_shufflevector(pA[2], pA[3], 0, 1, 2, 3, 4, 5, 6, 7);
    const bf16x8 BB0 = __builtin_shufflevector(pB[0], pB[1], 0, 1, 2, 3, 4, 5, 6, 7);
    const bf16x8 BB1 = __builtin_shufflevector(pB[2], pB[3], 0, 1, 2, 3, 4, 5, 6, 7);
    __builtin_amdgcn_s_setprio(1);
#pragma unroll
    for (int mt = 0; mt < 4; ++mt) {
        const int rv = mt * 16 + fr;
        const bf16x8 vk0 = *(const bf16x8*)(&Vs[SWZ64(rv, gg)]);
        const bf16x8 vk1 = *(const bf16x8*)(&Vs[SWZ64(rv, gg + 4)]);
        oA[mt] = __builtin_amdgcn_mfma_f32_16x16x32_bf16(vk0, BA0, oA[mt], 0, 0, 0);
        oA[mt] = __builtin_amdgcn_mfma_f32_16x16x32_bf16(vk1, BA1, oA[mt], 0, 0, 0);
        oB[mt] = __builtin_amdgcn_mfma_f32_16x16x32_bf16(vk0, BB0, oB[mt], 0, 0, 0);
        oB[mt] = __builtin_amdgcn_mfma_f32_16x16x32_bf16(vk1, BB1, oB[mt], 0, 0, 0);
    }
    sumA = __builtin_amdgcn_mfma_f32_16x16x32_bf16(ones, BA0, sumA, 0, 0, 0);
    sumA = __builtin_amdgcn_mfma_f32_16x16x32_bf16(ones, BA1, sumA, 0, 0, 0);
    sumB = __builtin_amdgcn_mfma_f32_16x16x32_bf16(ones, BB0, sumB, 0, 0, 0);
    sumB = __builtin_amdgcn_mfma_f32_16x16x32_bf16(ones, BB1, sumB, 0, 0, 0);
    __builtin_amdgcn_s_setprio(0);
}

// 1D grid 1024 blocks (XCD-bijective swizzle). 4 waves, 32 q-rows/wave (groups A/B).
// 2-slot K + 3-slot V rotation = 40 KB LDS. K and V staged at +1. Ledger: at iter t
// entry, outstanding = {K(t), V(t)}; vmcnt(2) lands K(t); only V(t) stays in flight.
__global__ __launch_bounds__(256, 2) void k_flash(const u16* __restrict__ Q, const u16* __restrict__ K,
                                                  const u16* __restrict__ Vt2, u16* __restrict__ O) {
    __shared__ u16 Ks[2][64 * 64];
    __shared__ u16 Vs[3][64 * 64];
    const int tid = threadIdx.x;
    const int l = tid & 63, w = tid >> 6;
    const int id = blockIdx.x;
    const int swz = (id & 7) * 128 + (id >> 3);      // bijective XCD swizzle (1024 % 8 == 0)
    const int bh = swz >> 3, qt = swz & 7;
    const int b = bh >> 4, h = bh & 15;
    const int qw = qt * 128 + w * 32;
    const int fr = l & 15, gg = l >> 4, f4 = gg * 4, f8 = gg * 8;

    const u16* qpA = Q + ((size_t)(b * 1024 + qw + fr)) * 1024 + h * 64 + f8;
    const u16* qpB = qpA + 16 * 1024;
    const bf16x8 qA0 = *(const bf16x8*)qpA;
    const bf16x8 qA1 = *(const bf16x8*)(qpA + 32);
    const bf16x8 qB0 = *(const bf16x8*)qpB;
    const bf16x8 qB1 = *(const bf16x8*)(qpB + 32);

    const __bf16 one1 = (__bf16)1.0f;
    const bf16x8 ones = {one1, one1, one1, one1, one1, one1, one1, one1};

    const int jj0 = w * 2, jj1 = w * 2 + 1;
    const int sr0 = jj0 * 8 + (l >> 3), sr1 = jj1 * 8 + (l >> 3);
    const int sc = ((l & 7) ^ (l >> 3)) * 8;
    const u16* kg0 = K + ((size_t)(b * 1024 + sr0)) * 1024 + h * 64 + sc;
    const u16* kg1 = K + ((size_t)(b * 1024 + sr1)) * 1024 + h * 64 + sc;
    const u16* vg0 = Vt2 + ((size_t)(h * 64 + sr0)) * 8192 + b * 1024 + sc;
    const u16* vg1 = Vt2 + ((size_t)(h * 64 + sr1)) * 8192 + b * 1024 + sc;
    const int lk0 = jj0 * 512 + l * 8, lk1 = jj1 * 512 + l * 8;

#define FSTGK(S, kt)                                        \
    gload16(kg0 + (size_t)(kt) * 1024, Ks[S] + lk0);        \
    gload16(kg1 + (size_t)(kt) * 1024, Ks[S] + lk1);
#define FSTGV(S, kt)                                        \
    gload16(vg0 + (kt), Vs[S] + lk0);                       \
    gload16(vg1 + (kt), Vs[S] + lk1);

    f32x4 oA[4] = {}, oB[4] = {};
    f32x4 sumA = {0.f, 0.f, 0.f, 0.f}, sumB = {0.f, 0.f, 0.f, 0.f};
    float mA = 0.f, mB = 0.f;                       // running log2-domain max offsets
    bf16x4 p0A[4], p0B[4], p1A[4], p1B[4];          // ping-pong P sets (static names)

    // prologue: K(0), V(0)  [issue order is the vmcnt ledger]
    FSTGK(0, 0) FSTGV(0, 0)

#define FITER(T, QS, PS, KS, VS, PCA, PCB, PPA, PPB, DOPV, DOSTG)            \
    {                                                                        \
        vm_wait<2>();                                                        \
        __builtin_amdgcn_s_barrier();                                        \
        f32x4 sA[4], sB[4];                                                  \
        qk_tile(Ks[QS], fr, gg, qA0, qA1, qB0, qB1, mA, mB, sA, sB);         \
        if (DOSTG) { FSTGK(KS, ((T) + 1) * 64) FSTGV(VS, ((T) + 1) * 64) }   \
        if (DOPV) pv_tile(Vs[PS], fr, gg, PPA, PPB, oA, oB, sumA, sumB, ones); \
        sm_tile(sA, oA, sumA, mA, PCA);                                      \
        sm_tile(sB, oB, sumB, mB, PCB);                                      \
    }

    FITER(0,  0, 0, 1, 1, p0A, p0B, p1A, p1B, 0, 1)
    FITER(1,  1, 0, 0, 2, p1A, p1B, p0A, p0B, 1, 1)
    FITER(2,  0, 1, 1, 0, p0A, p0B, p1A, p1B, 1, 1)
    FITER(3,  1, 2, 0, 1, p1A, p1B, p0A, p0B, 1, 1)
    FITER(4,  0, 0, 1, 2, p0A, p0B, p1A, p1B, 1, 1)
    FITER(5,  1, 1, 0, 0, p1A, p1B, p0A, p0B, 1, 1)
    FITER(6,  0, 2, 1, 1, p0A, p0B, p1A, p1B, 1, 1)
    FITER(7,  1, 0, 0, 2, p1A, p1B, p0A, p0B, 1, 1)
    FITER(8,  0, 1, 1, 0, p0A, p0B, p1A, p1B, 1, 1)
    FITER(9,  1, 2, 0, 1, p1A, p1B, p0A, p0B, 1, 1)
    FITER(10, 0, 0, 1, 2, p0A, p0B, p1A, p1B, 1, 1)
    FITER(11, 1, 1, 0, 0, p1A, p1B, p0A, p0B, 1, 1)
    FITER(12, 0, 2, 1, 1, p0A, p0B, p1A, p1B, 1, 1)
    FITER(13, 1, 0, 0, 2, p1A, p1B, p0A, p0B, 1, 1)
    FITER(14, 0, 1, 1, 0, p0A, p0B, p1A, p1B, 1, 1)
    FITER(15, 1, 2, 0, 0, p1A, p1B, p0A, p0B, 1, 0)
#undef FITER
    // drain: PV of tile 15; V(15) sits in Vs[0] (staged at T=14)
    vm_wait<0>();
    __builtin_amdgcn_s_barrier();
    pv_tile(Vs[0], fr, gg, p1A, p1B, oA, oB, sumA, sumB, ones);
#undef FSTGK
#undef FSTGV

    // epilogue: MFMA already summed the denominator across all 64 k per tile
    // (every C/D row equals the row sum; element 0 of this lane's acc suffices).
    const float ivA = 1.0f / sumA[0], ivB = 1.0f / sumB[0];
    u16* opA = O + ((size_t)(b * 1024 + qw + fr)) * 1024 + h * 64;
    u16* opB = opA + 16 * 1024;
#pragma unroll
    for (int mt = 0; mt < 4; ++mt) {
        u16x4 oa, ob;
#pragma unroll
        for (int r = 0; r < 4; ++r) { oa[r] = f2bf(oA[mt][r] * ivA); ob[r] = f2bf(oB[mt][r] * ivB); }
        *(u16x4*)(opA + mt * 16 + f4) = oa;
        *(u16x4*)(opB + mt * 16 + f4) = ob;
    }
}

extern "C" void kernel_launch(void* const* d_in, const int* in_sizes, int n_in,
                              void* d_out, int out_size, void* d_ws, size_t ws_size,
                              hipStream_t stream) {
    (void)in_sizes; (void)n_in; (void)out_size; (void)ws_size;
    const float* hs = (const float*)d_in[0];
    const float* Wq = (const float*)d_in[1];
    const float* bq = (const float*)d_in[2];
    const float* Wk = (const float*)d_in[3];
    const float* bk = (const float*)d_in[4];
    const float* Wv = (const float*)d_in[5];
    const float* bv = (const float*)d_in[6];
    const float* Wo = (const float*)d_in[7];
    const float* bo = (const float*)d_in[8];
    float* out = (float*)d_out;
    char* ws = (char*)d_ws;
    const size_t MB = 1024ull * 1024ull;
    u16* Xb  = (u16*)(ws);            // 16 MB (dead after V^T GEMM; reused as attn output Ob)
    u16* Wqt = (u16*)(ws + 16 * MB);  // 2 MB each; Wqt+Wkt adjacent => stacked [2048][1024]
    u16* Wkt = (u16*)(ws + 18 * MB);
    u16* Wvt = (u16*)(ws + 20 * MB);
    u16* Wot = (u16*)(ws + 22 * MB);
    u16* Qb  = (u16*)(ws + 24 * MB);  // 16 MB
    u16* Kb  = (u16*)(ws + 40 * MB);  // 16 MB
    u16* Vt2 = (u16*)(ws + 56 * MB);  // 16 MB: V^T[n][t-permuted], ld=8192 -> 72 MB total
    u16* Ob  = Xb;

    // HD^-0.5 * log2(e) folded into Wq and bq (softmax runs in log2 domain)
    const float SCALE_Q = 0.125f * 1.4426950408889634f;

    // merged convert + 4x weight transpose (independent memory-bound work, one launch)
    k_prep<<<dim3(12288), dim3(256), 0, stream>>>(hs, Xb, Wq, Wk, Wv, Wo,
                                                  Wqt, Wkt, Wvt, Wot, SCALE_Q);
    // fused Q+K projection: M=8192, N=2048 over stacked [Wqt;Wkt]; 32x8 = 256 blocks
    k_g256<256><<<dim3(256), dim3(512), 0, stream>>>(Xb, Wqt, bq, bk, SCALE_Q,
                                                     Qb, Kb, nullptr, 1024, 0, 8, 1);
    // V^T = Wv^T * X^T (k-permuted cols): A = Wvt (M=1024), Bt = Xb (N=8192); 4x64 blocks
    k_g256<128><<<dim3(256), dim3(512), 0, stream>>>(Wvt, Xb, bv, nullptr, 1.f,
                                                     Vt2, nullptr, nullptr, 8192, 1, 64, 2);
    k_flash<<<dim3(1024), dim3(256), 0, stream>>>(Qb, Kb, Vt2, Ob);
    // output projection: M=8192, N=1024, f32 out; 32x8 = 256 blocks
    k_g256<128><<<dim3(256), dim3(512), 0, stream>>>(Ob, Wot, bo, nullptr, 1.f,
                                                     nullptr, nullptr, out, 1024, 0, 8, 0);
}